// Round 3
// baseline (45.364 us; speedup 1.0000x reference)
//
#include <hip/hip_runtime.h>

#define BATCH 4096
#define FEAT_DIM 2048
#define NTHREADS 256
#define ROWS_PER_BLOCK 4                    // one wave64 per row
#define NBLOCKS (BATCH / ROWS_PER_BLOCK)    // 1024

// Single fused kernel:
//  - each wave computes ||x_row - c_{label}||^2 (clamped)
//  - block partial -> d_ws partial array (plain store, rewritten every call)
//  - ticket counter (mod trick: works from ANY initial counter value, incl.
//    the harness's 0xAA poison) elects exactly one "last" block per call,
//    which reduces the 1024 partials and writes the mean.
__global__ __launch_bounds__(NTHREADS) void cl_fused(
        const float* __restrict__ x,
        const int* __restrict__ labels,
        const float* __restrict__ centers,
        float* __restrict__ partial,
        unsigned int* __restrict__ counter,
        float* __restrict__ out) {
    const int tid  = threadIdx.x;
    const int wave = tid >> 6;
    const int lane = tid & 63;
    const int bid  = blockIdx.x;
    const int row  = bid * ROWS_PER_BLOCK + wave;

    const int lab = labels[row];
    const float4* __restrict__ xr =
        reinterpret_cast<const float4*>(x + (size_t)row * FEAT_DIM);
    const float4* __restrict__ cr =
        reinterpret_cast<const float4*>(centers + (size_t)lab * FEAT_DIM);

    // 2048 floats / 64 lanes = 8 float4 per lane per array, all independent.
    float4 a[8], b[8];
    #pragma unroll
    for (int k = 0; k < 8; ++k) a[k] = xr[lane + 64 * k];
    #pragma unroll
    for (int k = 0; k < 8; ++k) b[k] = cr[lane + 64 * k];

    float s = 0.f;
    #pragma unroll
    for (int k = 0; k < 8; ++k) {
        float dx = a[k].x - b[k].x;
        float dy = a[k].y - b[k].y;
        float dz = a[k].z - b[k].z;
        float dw = a[k].w - b[k].w;
        s += dx * dx + dy * dy + dz * dz + dw * dw;
    }

    // wave64 reduce
    #pragma unroll
    for (int off = 32; off > 0; off >>= 1) s += __shfl_down(s, off, 64);

    __shared__ float sw[ROWS_PER_BLOCK];
    __shared__ int is_winner;
    if (lane == 0) sw[wave] = fminf(fmaxf(s, 1e-12f), 1e12f);
    __syncthreads();

    if (tid == 0) {
        float t = sw[0] + sw[1] + sw[2] + sw[3];
        partial[bid] = t;
        __threadfence();                        // release: publish partial
        unsigned int old = atomicAdd(counter, 1u);
        is_winner = ((old & (NBLOCKS - 1)) == (NBLOCKS - 1)) ? 1 : 0;
    }
    __syncthreads();

    if (is_winner) {
        __threadfence();                        // acquire: see all partials
        float acc = 0.f;
        #pragma unroll
        for (int i = tid; i < NBLOCKS; i += NTHREADS) acc += partial[i];

        #pragma unroll
        for (int off = 32; off > 0; off >>= 1) acc += __shfl_down(acc, off, 64);

        __shared__ float fw[NTHREADS / 64];
        if ((tid & 63) == 0) fw[tid >> 6] = acc;
        __syncthreads();

        if (tid == 0) {
            float total = 0.f;
            #pragma unroll
            for (int w = 0; w < NTHREADS / 64; ++w) total += fw[w];
            out[0] = total * (1.0f / BATCH);
        }
    }
}

extern "C" void kernel_launch(void* const* d_in, const int* in_sizes, int n_in,
                              void* d_out, int out_size, void* d_ws, size_t ws_size,
                              hipStream_t stream) {
    const float* x       = (const float*)d_in[0];
    const int*   labels  = (const int*)d_in[1];
    const float* centers = (const float*)d_in[2];
    float*       out     = (float*)d_out;

    // d_ws layout: [0] ticket counter (4 B), partials at +4 KB (avoid sharing
    // a cache line with the hot atomic).
    unsigned int* counter = (unsigned int*)d_ws;
    float*        partial = (float*)((char*)d_ws + 4096);

    cl_fused<<<NBLOCKS, NTHREADS, 0, stream>>>(x, labels, centers,
                                               partial, counter, out);
}

// Round 4
// 17.760 us; speedup vs baseline: 2.5542x; 2.5542x over previous
//
#include <hip/hip_runtime.h>

#define BATCH 4096
#define FEAT_DIM 2048
#define NTHREADS 256
#define ROWS_PER_WAVE 2
#define WAVES_PER_BLOCK (NTHREADS / 64)                    // 4
#define ROWS_PER_BLOCK (ROWS_PER_WAVE * WAVES_PER_BLOCK)   // 8
#define NBLOCKS (BATCH / ROWS_PER_BLOCK)                   // 512

// Kernel A: each wave computes TWO rows' ||x - c_label||^2 (32 independent
// float4 loads in flight per lane for latency hiding). Block partial -> d_ws.
__global__ __launch_bounds__(NTHREADS) void cl_rows(
        const float* __restrict__ x,
        const int* __restrict__ labels,
        const float* __restrict__ centers,
        float* __restrict__ partial) {
    const int tid  = threadIdx.x;
    const int wave = tid >> 6;
    const int lane = tid & 63;
    const int row0 = blockIdx.x * ROWS_PER_BLOCK + wave * ROWS_PER_WAVE;
    const int row1 = row0 + 1;

    const int lab0 = labels[row0];
    const int lab1 = labels[row1];

    const float4* __restrict__ xr0 =
        reinterpret_cast<const float4*>(x + (size_t)row0 * FEAT_DIM);
    const float4* __restrict__ xr1 =
        reinterpret_cast<const float4*>(x + (size_t)row1 * FEAT_DIM);
    const float4* __restrict__ cr0 =
        reinterpret_cast<const float4*>(centers + (size_t)lab0 * FEAT_DIM);
    const float4* __restrict__ cr1 =
        reinterpret_cast<const float4*>(centers + (size_t)lab1 * FEAT_DIM);

    // 2048 floats / 64 lanes = 8 float4 per lane per array; 4 arrays = 32
    // independent loads in flight per lane.
    float4 a0[8], b0[8], a1[8], b1[8];
    #pragma unroll
    for (int k = 0; k < 8; ++k) a0[k] = xr0[lane + 64 * k];
    #pragma unroll
    for (int k = 0; k < 8; ++k) b0[k] = cr0[lane + 64 * k];
    #pragma unroll
    for (int k = 0; k < 8; ++k) a1[k] = xr1[lane + 64 * k];
    #pragma unroll
    for (int k = 0; k < 8; ++k) b1[k] = cr1[lane + 64 * k];

    float s0 = 0.f, s1 = 0.f;
    #pragma unroll
    for (int k = 0; k < 8; ++k) {
        float dx = a0[k].x - b0[k].x;
        float dy = a0[k].y - b0[k].y;
        float dz = a0[k].z - b0[k].z;
        float dw = a0[k].w - b0[k].w;
        s0 += dx * dx + dy * dy + dz * dz + dw * dw;
    }
    #pragma unroll
    for (int k = 0; k < 8; ++k) {
        float dx = a1[k].x - b1[k].x;
        float dy = a1[k].y - b1[k].y;
        float dz = a1[k].z - b1[k].z;
        float dw = a1[k].w - b1[k].w;
        s1 += dx * dx + dy * dy + dz * dz + dw * dw;
    }

    // wave64 reduce of both row-sums (clamped per row after full reduce)
    #pragma unroll
    for (int off = 32; off > 0; off >>= 1) {
        s0 += __shfl_down(s0, off, 64);
        s1 += __shfl_down(s1, off, 64);
    }

    __shared__ float sw[WAVES_PER_BLOCK];
    if (lane == 0) {
        float c0 = fminf(fmaxf(s0, 1e-12f), 1e12f);
        float c1 = fminf(fmaxf(s1, 1e-12f), 1e12f);
        sw[wave] = c0 + c1;
    }
    __syncthreads();

    if (tid == 0) {
        float t = 0.f;
        #pragma unroll
        for (int w = 0; w < WAVES_PER_BLOCK; ++w) t += sw[w];
        partial[blockIdx.x] = t;
    }
}

// Kernel B: reduce NBLOCKS partials, write the mean. Fixed order -> exact.
__global__ __launch_bounds__(NTHREADS) void cl_final(
        const float* __restrict__ partial,
        float* __restrict__ out) {
    const int tid = threadIdx.x;
    float s = 0.f;
    #pragma unroll
    for (int i = tid; i < NBLOCKS; i += NTHREADS) s += partial[i];

    #pragma unroll
    for (int off = 32; off > 0; off >>= 1) s += __shfl_down(s, off, 64);

    __shared__ float sw[NTHREADS / 64];
    if ((tid & 63) == 0) sw[tid >> 6] = s;
    __syncthreads();

    if (tid == 0) {
        float t = 0.f;
        #pragma unroll
        for (int w = 0; w < NTHREADS / 64; ++w) t += sw[w];
        out[0] = t * (1.0f / BATCH);
    }
}

extern "C" void kernel_launch(void* const* d_in, const int* in_sizes, int n_in,
                              void* d_out, int out_size, void* d_ws, size_t ws_size,
                              hipStream_t stream) {
    const float* x       = (const float*)d_in[0];
    const int*   labels  = (const int*)d_in[1];
    const float* centers = (const float*)d_in[2];
    float*       out     = (float*)d_out;
    float*       partial = (float*)d_ws;   // NBLOCKS floats = 2 KB

    cl_rows<<<NBLOCKS, NTHREADS, 0, stream>>>(x, labels, centers, partial);
    cl_final<<<1, NTHREADS, 0, stream>>>(partial, out);
}